// Round 7
// baseline (225.708 us; speedup 1.0000x reference)
//
#include <hip/hip_runtime.h>

typedef unsigned short ushort_t;
typedef __bf16 bf16x8 __attribute__((ext_vector_type(8)));
typedef float f32x4 __attribute__((ext_vector_type(4)));
typedef float f32x16 __attribute__((ext_vector_type(16)));
typedef unsigned short ushortx8 __attribute__((ext_vector_type(8)));
typedef unsigned int uintx4 __attribute__((ext_vector_type(4)));

#define NH 16
#define HS 64
#define CD 1024
#define NB 2
#define NT 2048
#define BT (NB * NT)   // 4096
#define N3 (3 * CD)    // 3072

#define L2E_DIV32 0.04508422002778011f  // log2(e) / 32  (scale = C^-0.5 = 1/32)

// workspace layout (bytes):
// 0        : Xbf 8MB  |  8388608: Wqkv_t 6MB   <- dead after QKV GEMM -> partial region0
// 14680064 : Wo_bf 2MB (live until last GEMM)
// 16777216 : QKV 16MB  [4096][2048] (Q cols 0-1023 prescaled, K cols 1024-2047)
// 33554432 : Vt 8MB    [2048 rows = b*1024+h*64+d][2048 t]
// 41943040 : Obf 8MB
// 50331648 : partial region1 (356 slots * 18432 -> ends 56893440; proven in R4)
#define QKV_LD 2048
#define PART1_OFF 50331648
#define SLOT_BYTES 18432      // 4 waves * (64 lanes * 64B O + 256B m + 256B l)
#define WAVE_BYTES 4608
#define R0_SLOTS 796

// ---------- helpers ----------

__device__ __forceinline__ ushort_t bf16_rne(float f) {
  union { float f; unsigned u; } v; v.f = f;
  unsigned u = v.u;
  unsigned r = (u + 0x7FFFu + ((u >> 16) & 1u)) >> 16;
  return (ushort_t)r;
}

__device__ __forceinline__ float bf2f(ushort_t u) {
  union { unsigned u; float f; } v; v.u = ((unsigned)u) << 16; return v.f;
}

__device__ __forceinline__ void gload_lds16(const ushort_t* g, ushort_t* l) {
  __builtin_amdgcn_global_load_lds(
      (const __attribute__((address_space(1))) unsigned int*)g,
      (__attribute__((address_space(3))) unsigned int*)l, 16, 0, 0);
}

__device__ __forceinline__ f32x4 mfma16(ushortx8 a, ushortx8 b, f32x4 c) {
  return __builtin_amdgcn_mfma_f32_16x16x32_bf16(
      __builtin_bit_cast(bf16x8, a), __builtin_bit_cast(bf16x8, b), c, 0, 0, 0);
}

__device__ __forceinline__ f32x16 mfma32(ushortx8 a, ushortx8 b, f32x16 c) {
  return __builtin_amdgcn_mfma_f32_32x32x16_bf16(
      __builtin_bit_cast(bf16x8, a), __builtin_bit_cast(bf16x8, b), c, 0, 0, 0);
}

__device__ __forceinline__ unsigned cvt_pk_bf16(float lo, float hi) {
  unsigned r;
  asm("v_cvt_pk_bf16_f32 %0, %1, %2" : "=v"(r) : "v"(lo), "v"(hi));
  return r;
}

__device__ __forceinline__ void plswap(unsigned &a, unsigned &b) {
  asm volatile("v_permlane32_swap_b32 %0, %1" : "+v"(a), "+v"(b));
}

// ---------- pack kernels ----------

__global__ __launch_bounds__(256)
void pack_cast(const float4* __restrict__ in, ushort_t* __restrict__ out, int n4) {
  const int i = blockIdx.x * 256 + threadIdx.x;
  if (i >= n4) return;
  const float4 v = in[i];
  ushort4 r;
  r.x = bf16_rne(v.x); r.y = bf16_rne(v.y);
  r.z = bf16_rne(v.z); r.w = bf16_rne(v.w);
  *(ushort4*)(out + (size_t)i * 4) = r;
}

// Wq/Wk/Wv: [H][C][HS] fp32 -> Wqkv_t bf16 [3072 rows = s*1024+h*64+d][1024 cols = c]
__global__ __launch_bounds__(256)
void pack_wqkv(const float* __restrict__ Wq, const float* __restrict__ Wk,
               const float* __restrict__ Wv, ushort_t* __restrict__ out) {
  __shared__ ushort_t tile[64 * 66];
  const int sh = blockIdx.y;
  const int s = sh >> 4, h = sh & 15;
  const float* W = (s == 0) ? Wq : ((s == 1) ? Wk : Wv);
  const int c0 = blockIdx.x * 64;
  const int t = threadIdx.x;
#pragma unroll
  for (int j = 0; j < 16; ++j) {
    const int idx = t + j * 256;
    const int ci = idx >> 6, d = idx & 63;
    const float v = W[(size_t)(h * 1024 + c0 + ci) * 64 + d];
    tile[d * 66 + ci] = bf16_rne(v);
  }
  __syncthreads();
#pragma unroll
  for (int j = 0; j < 16; ++j) {
    const int idx = t + j * 256;
    const int d = idx >> 6, ci = idx & 63;
    out[(size_t)(s * 1024 + h * 64 + d) * 1024 + c0 + ci] = tile[d * 66 + ci];
  }
}

// ---------- GEMM: C[m][n] = sum_k A[m][k] * Bt[n][k] ----------
// MODE 0: plain f32 output, ldc = N.
// MODE 1: QKV mode: col<1024 -> bf16*L2E_DIV32 to QKVo (ld 2048);
//         col in [1024,2048) -> bf16 to QKVo; col >= 2048 -> transposed to Vt.

template <int MODE>
__global__ __launch_bounds__(256)
void gemm_bt(const ushort_t* __restrict__ A, const ushort_t* __restrict__ Bt,
             void* __restrict__ Cv, ushort_t* __restrict__ Vt,
             int M, int N, int K) {
  __shared__ __align__(16) ushort_t ldsA[2][128 * 32];
  __shared__ __align__(16) ushort_t ldsB[2][128 * 32];
  const int tid = threadIdx.x;
  const int lane = tid & 63;
  const int wave = tid >> 6;
  const int row0 = blockIdx.y * 128;
  const int col0 = blockIdx.x * 128;
  const int wm = wave >> 1, wn = wave & 1;

  f32x4 acc[4][4] = {};

  const int ce = (tid & 3) * 8;

  auto stage = [&](int buf, int kt) {
    const int kbase = kt * 32;
#pragma unroll
    for (int j = 0; j < 2; ++j) {
      const int r = j * 64 + (tid >> 2);
      gload_lds16(A + (size_t)(row0 + r) * K + kbase + ce,
                  &ldsA[buf][(j * 256 + wave * 64) * 8]);
      gload_lds16(Bt + (size_t)(col0 + r) * K + kbase + ce,
                  &ldsB[buf][(j * 256 + wave * 64) * 8]);
    }
  };

  const int arow_off = (wm * 64 + (lane & 15)) * 32 + (lane >> 4) * 8;
  const int brow_off = (wn * 64 + (lane & 15)) * 32 + (lane >> 4) * 8;

  auto compute = [&](int buf) {
    ushortx8 af[4], bfr[4];
#pragma unroll
    for (int m = 0; m < 4; ++m)
      af[m] = *(const ushortx8*)&ldsA[buf][arow_off + m * 512];
#pragma unroll
    for (int n = 0; n < 4; ++n)
      bfr[n] = *(const ushortx8*)&ldsB[buf][brow_off + n * 512];
#pragma unroll
    for (int m = 0; m < 4; ++m)
#pragma unroll
      for (int n = 0; n < 4; ++n)
        acc[m][n] = mfma16(af[m], bfr[n], acc[m][n]);
  };

  stage(0, 0);
  __syncthreads();
  const int nk = K >> 5;
  for (int kt = 0; kt < nk; ++kt) {
    const int cur = kt & 1;
    if (kt + 1 < nk) stage(cur ^ 1, kt + 1);
    compute(cur);
    __syncthreads();
  }

#pragma unroll
  for (int m = 0; m < 4; ++m) {
    const int rbase = row0 + wm * 64 + m * 16 + (lane >> 4) * 4;
#pragma unroll
    for (int n = 0; n < 4; ++n) {
      const int col = col0 + wn * 64 + n * 16 + (lane & 15);
      if constexpr (MODE == 0) {
#pragma unroll
        for (int i = 0; i < 4; ++i)
          ((float*)Cv)[(size_t)(rbase + i) * N + col] = acc[m][n][i];
      } else {
        if (col < 2048) {
          const float sc = (col < 1024) ? L2E_DIV32 : 1.0f;
#pragma unroll
          for (int i = 0; i < 4; ++i)
            ((ushort_t*)Cv)[(size_t)(rbase + i) * QKV_LD + col] =
                bf16_rne(acc[m][n][i] * sc);
        } else {
          // V: write transposed. Vt row = b*1024 + (col-2048), col = t
          const int dcol = col - 2048;
          const int bI = rbase >> 11;
          const int t0i = rbase & 2047;
          ushort4 pk;
          pk.x = bf16_rne(acc[m][n][0]);
          pk.y = bf16_rne(acc[m][n][1]);
          pk.z = bf16_rne(acc[m][n][2]);
          pk.w = bf16_rne(acc[m][n][3]);
          *(ushort4*)(Vt + (size_t)(bI * 1024 + dcol) * NT + t0i) = pk;
        }
      }
    }
  }
}

// ---------- causal flash attention v6 ----------
// = R5 staging (K and V^T both via swizzled global_load_lds, counted vmcnt,
//   2 s_barriers) + R4-proven defer-max online softmax (m,l partials).

__global__ __launch_bounds__(256, 5)
void attn_fwd6(const ushort_t* __restrict__ QKV, const ushort_t* __restrict__ Vt,
               ushort_t* __restrict__ O, char* __restrict__ wsb) {
  __shared__ __align__(16) ushort_t Klds[2][64 * 64];   // [key][d]
  __shared__ __align__(16) ushort_t Vlds[2][64 * 64];   // [d][key]

  const int tid = threadIdx.x;
  const int lane = tid & 63;
  const int w = tid >> 6;
  const int l31 = lane & 31;
  const int h = lane >> 5;

  // block decode: bh in low 5 bits (XCD spread), chunk id c with longest-first
  const int x = blockIdx.x;
  const int bh = x & 31;
  const int c = x >> 5;  // 0..39
  int qb, j, k;
  if (c < 16)      { qb = 12 + (c >> 2); j = c & 3; k = 4; }
  else if (c < 28) { const int e = c - 16; const int q = e / 3; qb = 8 + q; j = e - q * 3; k = 3; }
  else if (c < 36) { const int e = c - 28; qb = 4 + (e >> 1); j = e & 1; k = 2; }
  else             { qb = c - 36; j = 0; k = 1; }
  const int nt = 2 * qb + 2;
  const int bsz = nt / k, rem = nt - bsz * k;
  const int t0 = j * bsz + (j < rem ? j : rem);
  const int t1 = t0 + bsz + (j < rem ? 1 : 0);
  const bool lastc = (t1 == nt);

  const int b = bh >> 4, head = bh & 15;
  const size_t base = (size_t)b * NT * QKV_LD;
  const int qg = qb * 128 + w * 32 + l31;
  const int tmax = lastc ? (2 * qb + (w >> 1)) : (t1 - 1);

  // ---- Q fragments (pre-scaled by log2(e)/32 in QKV GEMM) ----
  ushortx8 qf[4];
  {
    const ushort_t* qp = QKV + base + (size_t)qg * QKV_LD + head * 64 + h * 8;
#pragma unroll
    for (int kc = 0; kc < 4; ++kc) qf[kc] = *(const ushortx8*)(qp + kc * 16);
  }
  asm volatile("s_waitcnt vmcnt(0)" ::: "memory");  // clean vmcnt counting in-loop

  // ---- loop-invariant LDS byte offsets (shared by K-frag and V-frag reads) ----
  int koff[4];
#pragma unroll
  for (int kc = 0; kc < 4; ++kc)
    koff[kc] = l31 * 128 + (((2 * kc + h) ^ (l31 & 7)) * 16);

  // ---- staging source pointers at tile t0 ----
  const int rowA = tid >> 3, ccA = tid & 7;
  const int rowB = 32 + rowA;
  const ushort_t* kg = QKV + base + 1024 + head * 64;
  const ushort_t* vg = Vt + (size_t)(bh * 64) * NT;
  const ushort_t* ksA = kg + (size_t)(t0 * 64 + rowA) * QKV_LD + ((ccA ^ (rowA & 7)) * 8);
  const ushort_t* ksB = kg + (size_t)(t0 * 64 + rowB) * QKV_LD + ((ccA ^ (rowB & 7)) * 8);
  const ushort_t* vsA = vg + (size_t)rowA * NT + t0 * 64 + ((ccA ^ (rowA & 7)) * 8);
  const ushort_t* vsB = vg + (size_t)rowB * NT + t0 * 64 + ((ccA ^ (rowB & 7)) * 8);
  const size_t kadv = (size_t)64 * QKV_LD;

  f32x16 oA = {}, oB = {};
  float m_r = -INFINITY, l_r = 0.f;

  // ---- prologue: stage tile t0 into buffer 0 (4 gload_lds) ----
  gload_lds16(ksA, &Klds[0][(w * 64) * 8]);
  gload_lds16(ksB, &Klds[0][(256 + w * 64) * 8]);
  gload_lds16(vsA, &Vlds[0][(w * 64) * 8]);
  gload_lds16(vsB, &Vlds[0][(256 + w * 64) * 8]);

  int curb = 0;
  for (int t = t0; t < t1; ++t) {
    const bool hasn = (t + 1 < t1);
    const int nxt = curb ^ 1;
    if (hasn) {
      ksA += kadv; ksB += kadv; vsA += 64; vsB += 64;
      gload_lds16(ksA, &Klds[nxt][(w * 64) * 8]);
      gload_lds16(ksB, &Klds[nxt][(256 + w * 64) * 8]);
      gload_lds16(vsA, &Vlds[nxt][(w * 64) * 8]);
      gload_lds16(vsB, &Vlds[nxt][(256 + w * 64) * 8]);
      asm volatile("s_waitcnt vmcnt(4)" ::: "memory");  // tile t landed; t+1 flying
    } else {
      asm volatile("s_waitcnt vmcnt(0)" ::: "memory");
    }
    __builtin_amdgcn_s_barrier();
    asm volatile("" ::: "memory");

    if (t <= tmax) {
      const bool diag = lastc && (t == tmax);
      const bool halfB = diag && ((w & 1) == 0);  // upper 32 keys fully masked
      const char* kb = (const char*)&Klds[curb][0];
      const char* vb = (const char*)&Vlds[curb][0];

      // --- S^T = K Q^T (log2 units, scale pre-folded) ---
      f32x16 sA = {}, sB = {};
#pragma unroll
      for (int kc = 0; kc < 4; ++kc)
        sA = mfma32(*(const ushortx8*)(kb + koff[kc]), qf[kc], sA);
      if (!halfB) {
#pragma unroll
        for (int kc = 0; kc < 4; ++kc)
          sB = mfma32(*(const ushortx8*)(kb + 4096 + koff[kc]), qf[kc], sB);
      }

      // --- causal mask (diag tiles only) ---
      if (diag) {
#pragma unroll
        for (int r = 0; r < 16; ++r) {
          const int krow = (r & 3) + 8 * (r >> 2) + 4 * h;
          if (halfB) { if (krow > l31) sA[r] = -INFINITY; }
          else       { if (krow > l31) sB[r] = -INFINITY; }
        }
      }

      // --- row max (tree) ---
      float mm[16];
#pragma unroll
      for (int r = 0; r < 16; ++r) mm[r] = halfB ? sA[r] : fmaxf(sA[r], sB[r]);
#pragma unroll
      for (int st = 8; st >= 1; st >>= 1)
#pragma unroll
        for (int r = 0; r < st; ++r) mm[r] = fmaxf(mm[r], mm[r + st]);
      const float mx = fmaxf(mm[0], __shfl_xor(mm[0], 32, 64));

      // --- deferred-max rescale (THR=8 in log2 domain) ---
      if (__any(mx > m_r + 8.0f)) {
        const float mn = fmaxf(m_r, mx);
        const float al = exp2f(m_r - mn);
        m_r = mn; l_r *= al;
#pragma unroll
        for (int r = 0; r < 16; ++r) { oA[r] *= al; oB[r] *= al; }
      }

      // --- exp2 + pack bf16 + partial sums ---
      unsigned u[16];
      float ps[8];
#pragma unroll
      for (int jj = 0; jj < 8; ++jj) {
        const float e0 = exp2f(sA[2 * jj] - m_r);
        const float e1 = exp2f(sA[2 * jj + 1] - m_r);
        u[jj] = cvt_pk_bf16(e0, e1);
        ps[jj] = e0 + e1;
      }
      if (!halfB) {
#pragma unroll
        for (int jj = 0; jj < 8; ++jj) {
          const float e0 = exp2f(sB[2 * jj] - m_r);
          const float e1 = exp2f(sB[2 * jj + 1] - m_r);
          u[8 + jj] = cvt_pk_bf16(e0, e1);
          ps[jj] += e0 + e1;
        }
      }
#pragma unroll
      for (int st = 4; st >= 1; st >>= 1)
#pragma unroll
        for (int r = 0; r < st; ++r) ps[r] += ps[r + st];
      l_r += ps[0] + __shfl_xor(ps[0], 32, 64);

      // --- P^T B-frags via permlane32 swaps ---
      plswap(u[0], u[2]);   plswap(u[1], u[3]);
      plswap(u[4], u[6]);   plswap(u[5], u[7]);
      if (!halfB) {
        plswap(u[8], u[10]);  plswap(u[9], u[11]);
        plswap(u[12], u[14]); plswap(u[13], u[15]);
      }

      // --- O^T += V^T P^T ---
#pragma unroll
      for (int kc = 0; kc < 4; ++kc) {
        if (kc < 2 || !halfB) {
          uintx4 pw;
          pw[0] = u[4 * kc + 0]; pw[1] = u[4 * kc + 1];
          pw[2] = u[4 * kc + 2]; pw[3] = u[4 * kc + 3];
          const ushortx8 pav = __builtin_bit_cast(ushortx8, pw);
          oA = mfma32(*(const ushortx8*)(vb + koff[kc]), pav, oA);
          oB = mfma32(*(const ushortx8*)(vb + 4096 + koff[kc]), pav, oB);
        }
      }
    }

    __builtin_amdgcn_s_barrier();   // all reads of buf curb done before overwrite
    asm volatile("" ::: "memory");
    curb ^= 1;
  }

  // ---- epilogue ----
  if (k == 1) {
    const float inv_l = 1.0f / l_r;
    ushort_t* op = O + ((size_t)(b * NT + qg)) * 1024 + head * 64;
#pragma unroll
    for (int db = 0; db < 2; ++db)
#pragma unroll
      for (int g = 0; g < 4; ++g) {
        ushort4 pk;
        pk.x = bf16_rne((db ? oB[4 * g + 0] : oA[4 * g + 0]) * inv_l);
        pk.y = bf16_rne((db ? oB[4 * g + 1] : oA[4 * g + 1]) * inv_l);
        pk.z = bf16_rne((db ? oB[4 * g + 2] : oA[4 * g + 2]) * inv_l);
        pk.w = bf16_rne((db ? oB[4 * g + 3] : oA[4 * g + 3]) * inv_l);
        *(ushort4*)(op + db * 32 + 8 * g + 4 * h) = pk;
      }
  } else {
    const int local = (qb < 8) ? ((qb - 4) * 2 + j)
                    : (qb < 12) ? (8 + (qb - 8) * 3 + j)
                    : (20 + (qb - 12) * 4 + j);
    const int s = bh * 36 + local;
    char* wb = (s < R0_SLOTS ? wsb + (size_t)s * SLOT_BYTES
                             : wsb + PART1_OFF + (size_t)(s - R0_SLOTS) * SLOT_BYTES)
               + w * WAVE_BYTES;
#pragma unroll
    for (int g = 0; g < 4; ++g) {
      ushortx8 pk;
#pragma unroll
      for (int e2 = 0; e2 < 8; ++e2)
        pk[e2] = bf16_rne(g < 2 ? oA[g * 8 + e2] : oB[(g - 2) * 8 + e2]);
      *(ushortx8*)(wb + lane * 64 + g * 16) = pk;
    }
    *(float*)(wb + 4096 + lane * 4) = m_r;
    *(float*)(wb + 4352 + lane * 4) = l_r;
  }
}

// ---------- merge partials for qb >= 4 (max-weighted, R4-proven) ----------
__global__ __launch_bounds__(256)
void attn_merge(const char* __restrict__ wsb, ushort_t* __restrict__ O) {
  const int x = blockIdx.x;   // 384 = 32 bh * 12 qb
  const int bh = x & 31;
  const int qi = x >> 5;      // 0..11 -> qb 4..15
  const int qb = 4 + qi;
  const int k  = qi < 4 ? 2 : (qi < 8 ? 3 : 4);
  const int lb = qi < 4 ? qi * 2 : (qi < 8 ? 8 + (qi - 4) * 3 : 20 + (qi - 8) * 4);
  const int tid = threadIdx.x;
  const int lane = tid & 63;
  const int w = tid >> 6;
  const int l31 = lane & 31;
  const int h = lane >> 5;

  const char* wbs[4];
  float mj[4], lj[4];
  float M = -INFINITY;
#pragma unroll
  for (int jj = 0; jj < 4; ++jj) {
    if (jj < k) {
      const int s = bh * 36 + lb + jj;
      const char* wb = (s < R0_SLOTS ? wsb + (size_t)s * SLOT_BYTES
                                     : wsb + PART1_OFF + (size_t)(s - R0_SLOTS) * SLOT_BYTES)
                       + w * WAVE_BYTES;
      wbs[jj] = wb;
      mj[jj] = *(const float*)(wb + 4096 + lane * 4);
      lj[jj] = *(const float*)(wb + 4352 + lane * 4);
      M = fmaxf(M, mj[jj]);
    }
  }
  float o[32];
#pragma unroll
  for (int r = 0; r < 32; ++r) o[r] = 0.f;
  float lacc = 0.f;
#pragma unroll
  for (int jj = 0; jj < 4; ++jj) {
    if (jj < k) {
      const float a = exp2f(mj[jj] - M);
      lacc += a * lj[jj];
#pragma unroll
      for (int g = 0; g < 4; ++g) {
        const ushortx8 v = *(const ushortx8*)(wbs[jj] + lane * 64 + g * 16);
#pragma unroll
        for (int e = 0; e < 8; ++e) o[g * 8 + e] += a * bf2f(v[e]);
      }
    }
  }
  const float inv_l = 1.0f / lacc;
  const int b = bh >> 4, head = bh & 15;
  const int qg = qb * 128 + w * 32 + l31;
  ushort_t* op = O + ((size_t)(b * NT + qg)) * 1024 + head * 64;
#pragma unroll
  for (int db = 0; db < 2; ++db)
#pragma unroll
    for (int g = 0; g < 4; ++g) {
      ushort4 pk;
      pk.x = bf16_rne(o[db * 16 + 4 * g + 0] * inv_l);
      pk.y = bf16_rne(o[db * 16 + 4 * g + 1] * inv_l);
      pk.z = bf16_rne(o[db * 16 + 4 * g + 2] * inv_l);
      pk.w = bf16_rne(o[db * 16 + 4 * g + 3] * inv_l);
      *(ushort4*)(op + db * 32 + 8 * g + 4 * h) = pk;
    }
}

// ---------- launch ----------

extern "C" void kernel_launch(void* const* d_in, const int* in_sizes, int n_in,
                              void* d_out, int out_size, void* d_ws, size_t ws_size,
                              hipStream_t stream) {
  (void)in_sizes; (void)n_in; (void)out_size; (void)ws_size;
  const float* x  = (const float*)d_in[0];
  const float* Wq = (const float*)d_in[1];
  const float* Wk = (const float*)d_in[2];
  const float* Wv = (const float*)d_in[3];
  const float* Wo = (const float*)d_in[4];

  char* ws = (char*)d_ws;
  ushort_t* Xbf    = (ushort_t*)(ws);                        // 4096x1024 bf16 (8 MB)
  ushort_t* Wqkv_t = (ushort_t*)(ws + 8388608);              // 3072x1024 bf16 (6 MB)
  ushort_t* Wo_bf  = (ushort_t*)(ws + 14680064);             // 1024x1024 bf16 (2 MB)
  ushort_t* QKV    = (ushort_t*)(ws + 16777216);             // 4096x2048 bf16 (16 MB)
  ushort_t* Vt     = (ushort_t*)(ws + 33554432);             // 2048x2048 bf16 (8 MB)
  ushort_t* Obf    = (ushort_t*)(ws + 41943040);             // 4096x1024 bf16 (8 MB)

  pack_cast<<<4096, 256, 0, stream>>>((const float4*)x, Xbf, 1048576);
  pack_cast<<<1024, 256, 0, stream>>>((const float4*)Wo, Wo_bf, 262144);
  pack_wqkv<<<dim3(16, 48), 256, 0, stream>>>(Wq, Wk, Wv, Wqkv_t);

  gemm_bt<1><<<dim3(24, 32), 256, 0, stream>>>(Xbf, Wqkv_t, QKV, Vt, BT, N3, CD);
  attn_fwd6<<<1280, 256, 0, stream>>>(QKV, Vt, Obf, ws);
  attn_merge<<<384, 256, 0, stream>>>(ws, Obf);
  gemm_bt<0><<<dim3(8, 32), 256, 0, stream>>>(Obf, Wo_bf, d_out, nullptr, BT, CD, CD);
}

// Round 8
// 132.924 us; speedup vs baseline: 1.6980x; 1.6980x over previous
//
#include <hip/hip_runtime.h>

typedef unsigned short ushort_t;
typedef __bf16 bf16x8 __attribute__((ext_vector_type(8)));
typedef float f32x4 __attribute__((ext_vector_type(4)));
typedef float f32x16 __attribute__((ext_vector_type(16)));
typedef unsigned short ushortx8 __attribute__((ext_vector_type(8)));
typedef unsigned int uintx4 __attribute__((ext_vector_type(4)));

#define NH 16
#define HS 64
#define CD 1024
#define NB 2
#define NT 2048
#define BT (NB * NT)   // 4096
#define N3 (3 * CD)    // 3072

#define L2E_DIV32 0.04508422002778011f  // log2(e) / 32  (scale = C^-0.5 = 1/32)

// workspace layout (bytes):
// 0        : Xbf 8MB  |  8388608: Wqkv_t 6MB   <- dead after QKV GEMM -> partial region0
// 14680064 : Wo_bf 2MB (live until last GEMM)
// 16777216 : QKV 16MB  [4096][2048] (Q cols 0-1023 prescaled, K cols 1024-2047)
// 33554432 : Vt 8MB    [2048 rows = b*1024+h*64+d][2048 t]
// 41943040 : Obf 8MB
// 50331648 : partial region1 (356 slots * 18432 -> ends 56893440; proven in R4)
#define QKV_LD 2048
#define PART1_OFF 50331648
#define SLOT_BYTES 18432      // 4 waves * (64 lanes * 64B O + 256B m + 256B l)
#define WAVE_BYTES 4608
#define R0_SLOTS 796

// ---------- helpers ----------

__device__ __forceinline__ ushort_t bf16_rne(float f) {
  union { float f; unsigned u; } v; v.f = f;
  unsigned u = v.u;
  unsigned r = (u + 0x7FFFu + ((u >> 16) & 1u)) >> 16;
  return (ushort_t)r;
}

__device__ __forceinline__ float bf2f(ushort_t u) {
  union { unsigned u; float f; } v; v.u = ((unsigned)u) << 16; return v.f;
}

__device__ __forceinline__ void gload_lds16(const ushort_t* g, ushort_t* l) {
  __builtin_amdgcn_global_load_lds(
      (const __attribute__((address_space(1))) unsigned int*)g,
      (__attribute__((address_space(3))) unsigned int*)l, 16, 0, 0);
}

__device__ __forceinline__ f32x4 mfma16(ushortx8 a, ushortx8 b, f32x4 c) {
  return __builtin_amdgcn_mfma_f32_16x16x32_bf16(
      __builtin_bit_cast(bf16x8, a), __builtin_bit_cast(bf16x8, b), c, 0, 0, 0);
}

__device__ __forceinline__ f32x16 mfma32(ushortx8 a, ushortx8 b, f32x16 c) {
  return __builtin_amdgcn_mfma_f32_32x32x16_bf16(
      __builtin_bit_cast(bf16x8, a), __builtin_bit_cast(bf16x8, b), c, 0, 0, 0);
}

__device__ __forceinline__ unsigned cvt_pk_bf16(float lo, float hi) {
  unsigned r;
  asm("v_cvt_pk_bf16_f32 %0, %1, %2" : "=v"(r) : "v"(lo), "v"(hi));
  return r;
}

__device__ __forceinline__ void plswap(unsigned &a, unsigned &b) {
  asm volatile("v_permlane32_swap_b32 %0, %1" : "+v"(a), "+v"(b));
}

// ---------- pack kernels ----------

__global__ __launch_bounds__(256)
void pack_cast(const float4* __restrict__ in, ushort_t* __restrict__ out, int n4) {
  const int i = blockIdx.x * 256 + threadIdx.x;
  if (i >= n4) return;
  const float4 v = in[i];
  ushort4 r;
  r.x = bf16_rne(v.x); r.y = bf16_rne(v.y);
  r.z = bf16_rne(v.z); r.w = bf16_rne(v.w);
  *(ushort4*)(out + (size_t)i * 4) = r;
}

// Wq/Wk/Wv: [H][C][HS] fp32 -> Wqkv_t bf16 [3072 rows = s*1024+h*64+d][1024 cols = c]
__global__ __launch_bounds__(256)
void pack_wqkv(const float* __restrict__ Wq, const float* __restrict__ Wk,
               const float* __restrict__ Wv, ushort_t* __restrict__ out) {
  __shared__ ushort_t tile[64 * 66];
  const int sh = blockIdx.y;
  const int s = sh >> 4, h = sh & 15;
  const float* W = (s == 0) ? Wq : ((s == 1) ? Wk : Wv);
  const int c0 = blockIdx.x * 64;
  const int t = threadIdx.x;
#pragma unroll
  for (int j = 0; j < 16; ++j) {
    const int idx = t + j * 256;
    const int ci = idx >> 6, d = idx & 63;
    const float v = W[(size_t)(h * 1024 + c0 + ci) * 64 + d];
    tile[d * 66 + ci] = bf16_rne(v);
  }
  __syncthreads();
#pragma unroll
  for (int j = 0; j < 16; ++j) {
    const int idx = t + j * 256;
    const int d = idx >> 6, ci = idx & 63;
    out[(size_t)(s * 1024 + h * 64 + d) * 1024 + c0 + ci] = tile[d * 66 + ci];
  }
}

// ---------- GEMM: C[m][n] = sum_k A[m][k] * Bt[n][k] ----------
// MODE 0: plain f32 output, ldc = N.
// MODE 1: QKV mode: col<1024 -> bf16*L2E_DIV32 to QKVo (ld 2048);
//         col in [1024,2048) -> bf16 to QKVo; col >= 2048 -> transposed to Vt.

template <int MODE>
__global__ __launch_bounds__(256)
void gemm_bt(const ushort_t* __restrict__ A, const ushort_t* __restrict__ Bt,
             void* __restrict__ Cv, ushort_t* __restrict__ Vt,
             int M, int N, int K) {
  __shared__ __align__(16) ushort_t ldsA[2][128 * 32];
  __shared__ __align__(16) ushort_t ldsB[2][128 * 32];
  const int tid = threadIdx.x;
  const int lane = tid & 63;
  const int wave = tid >> 6;
  const int row0 = blockIdx.y * 128;
  const int col0 = blockIdx.x * 128;
  const int wm = wave >> 1, wn = wave & 1;

  f32x4 acc[4][4] = {};

  const int ce = (tid & 3) * 8;

  auto stage = [&](int buf, int kt) {
    const int kbase = kt * 32;
#pragma unroll
    for (int j = 0; j < 2; ++j) {
      const int r = j * 64 + (tid >> 2);
      gload_lds16(A + (size_t)(row0 + r) * K + kbase + ce,
                  &ldsA[buf][(j * 256 + wave * 64) * 8]);
      gload_lds16(Bt + (size_t)(col0 + r) * K + kbase + ce,
                  &ldsB[buf][(j * 256 + wave * 64) * 8]);
    }
  };

  const int arow_off = (wm * 64 + (lane & 15)) * 32 + (lane >> 4) * 8;
  const int brow_off = (wn * 64 + (lane & 15)) * 32 + (lane >> 4) * 8;

  auto compute = [&](int buf) {
    ushortx8 af[4], bfr[4];
#pragma unroll
    for (int m = 0; m < 4; ++m)
      af[m] = *(const ushortx8*)&ldsA[buf][arow_off + m * 512];
#pragma unroll
    for (int n = 0; n < 4; ++n)
      bfr[n] = *(const ushortx8*)&ldsB[buf][brow_off + n * 512];
#pragma unroll
    for (int m = 0; m < 4; ++m)
#pragma unroll
      for (int n = 0; n < 4; ++n)
        acc[m][n] = mfma16(af[m], bfr[n], acc[m][n]);
  };

  stage(0, 0);
  __syncthreads();
  const int nk = K >> 5;
  for (int kt = 0; kt < nk; ++kt) {
    const int cur = kt & 1;
    if (kt + 1 < nk) stage(cur ^ 1, kt + 1);
    compute(cur);
    __syncthreads();
  }

#pragma unroll
  for (int m = 0; m < 4; ++m) {
    const int rbase = row0 + wm * 64 + m * 16 + (lane >> 4) * 4;
#pragma unroll
    for (int n = 0; n < 4; ++n) {
      const int col = col0 + wn * 64 + n * 16 + (lane & 15);
      if constexpr (MODE == 0) {
#pragma unroll
        for (int i = 0; i < 4; ++i)
          ((float*)Cv)[(size_t)(rbase + i) * N + col] = acc[m][n][i];
      } else {
        if (col < 2048) {
          const float sc = (col < 1024) ? L2E_DIV32 : 1.0f;
#pragma unroll
          for (int i = 0; i < 4; ++i)
            ((ushort_t*)Cv)[(size_t)(rbase + i) * QKV_LD + col] =
                bf16_rne(acc[m][n][i] * sc);
        } else {
          // V: write transposed. Vt row = b*1024 + (col-2048), col = t
          const int dcol = col - 2048;
          const int bI = rbase >> 11;
          const int t0i = rbase & 2047;
          ushort4 pk;
          pk.x = bf16_rne(acc[m][n][0]);
          pk.y = bf16_rne(acc[m][n][1]);
          pk.z = bf16_rne(acc[m][n][2]);
          pk.w = bf16_rne(acc[m][n][3]);
          *(ushort4*)(Vt + (size_t)(bI * 1024 + dcol) * NT + t0i) = pk;
        }
      }
    }
  }
}

// ---------- causal flash attention v7 = v6 with spill-free launch bounds ----------
// K and V^T both staged via swizzled global_load_lds, counted vmcnt, 2 s_barriers,
// defer-max online softmax. __launch_bounds__(256,3): ~170-reg budget, no scratch.

__global__ __launch_bounds__(256, 3)
void attn_fwd7(const ushort_t* __restrict__ QKV, const ushort_t* __restrict__ Vt,
               ushort_t* __restrict__ O, char* __restrict__ wsb) {
  __shared__ __align__(16) ushort_t Klds[2][64 * 64];   // [key][d]
  __shared__ __align__(16) ushort_t Vlds[2][64 * 64];   // [d][key]

  const int tid = threadIdx.x;
  const int lane = tid & 63;
  const int w = tid >> 6;
  const int l31 = lane & 31;
  const int h = lane >> 5;

  // block decode: bh in low 5 bits (XCD spread), chunk id c with longest-first
  const int x = blockIdx.x;
  const int bh = x & 31;
  const int c = x >> 5;  // 0..39
  int qb, j, k;
  if (c < 16)      { qb = 12 + (c >> 2); j = c & 3; k = 4; }
  else if (c < 28) { const int e = c - 16; const int q = e / 3; qb = 8 + q; j = e - q * 3; k = 3; }
  else if (c < 36) { const int e = c - 28; qb = 4 + (e >> 1); j = e & 1; k = 2; }
  else             { qb = c - 36; j = 0; k = 1; }
  const int nt = 2 * qb + 2;
  const int bsz = nt / k, rem = nt - bsz * k;
  const int t0 = j * bsz + (j < rem ? j : rem);
  const int t1 = t0 + bsz + (j < rem ? 1 : 0);
  const bool lastc = (t1 == nt);

  const int b = bh >> 4, head = bh & 15;
  const size_t base = (size_t)b * NT * QKV_LD;
  const int qg = qb * 128 + w * 32 + l31;
  const int tmax = lastc ? (2 * qb + (w >> 1)) : (t1 - 1);

  // ---- Q fragments (pre-scaled by log2(e)/32 in QKV GEMM) ----
  ushortx8 qf[4];
  {
    const ushort_t* qp = QKV + base + (size_t)qg * QKV_LD + head * 64 + h * 8;
#pragma unroll
    for (int kc = 0; kc < 4; ++kc) qf[kc] = *(const ushortx8*)(qp + kc * 16);
  }
  asm volatile("s_waitcnt vmcnt(0)" ::: "memory");  // clean vmcnt counting in-loop

  // ---- loop-invariant LDS byte offsets (shared by K-frag and V-frag reads) ----
  int koff[4];
#pragma unroll
  for (int kc = 0; kc < 4; ++kc)
    koff[kc] = l31 * 128 + (((2 * kc + h) ^ (l31 & 7)) * 16);

  // ---- staging source pointers at tile t0 ----
  const int rowA = tid >> 3, ccA = tid & 7;
  const int rowB = 32 + rowA;
  const ushort_t* kg = QKV + base + 1024 + head * 64;
  const ushort_t* vg = Vt + (size_t)(bh * 64) * NT;
  const ushort_t* ksA = kg + (size_t)(t0 * 64 + rowA) * QKV_LD + ((ccA ^ (rowA & 7)) * 8);
  const ushort_t* ksB = kg + (size_t)(t0 * 64 + rowB) * QKV_LD + ((ccA ^ (rowB & 7)) * 8);
  const ushort_t* vsA = vg + (size_t)rowA * NT + t0 * 64 + ((ccA ^ (rowA & 7)) * 8);
  const ushort_t* vsB = vg + (size_t)rowB * NT + t0 * 64 + ((ccA ^ (rowB & 7)) * 8);
  const size_t kadv = (size_t)64 * QKV_LD;

  f32x16 oA = {}, oB = {};
  float m_r = -INFINITY, l_r = 0.f;

  // ---- prologue: stage tile t0 into buffer 0 (4 gload_lds) ----
  gload_lds16(ksA, &Klds[0][(w * 64) * 8]);
  gload_lds16(ksB, &Klds[0][(256 + w * 64) * 8]);
  gload_lds16(vsA, &Vlds[0][(w * 64) * 8]);
  gload_lds16(vsB, &Vlds[0][(256 + w * 64) * 8]);

  int curb = 0;
  for (int t = t0; t < t1; ++t) {
    const bool hasn = (t + 1 < t1);
    const int nxt = curb ^ 1;
    if (hasn) {
      ksA += kadv; ksB += kadv; vsA += 64; vsB += 64;
      gload_lds16(ksA, &Klds[nxt][(w * 64) * 8]);
      gload_lds16(ksB, &Klds[nxt][(256 + w * 64) * 8]);
      gload_lds16(vsA, &Vlds[nxt][(w * 64) * 8]);
      gload_lds16(vsB, &Vlds[nxt][(256 + w * 64) * 8]);
      asm volatile("s_waitcnt vmcnt(4)" ::: "memory");  // tile t landed; t+1 flying
    } else {
      asm volatile("s_waitcnt vmcnt(0)" ::: "memory");
    }
    __builtin_amdgcn_s_barrier();
    asm volatile("" ::: "memory");

    if (t <= tmax) {
      const bool diag = lastc && (t == tmax);
      const bool halfB = diag && ((w & 1) == 0);  // upper 32 keys fully masked
      const char* kb = (const char*)&Klds[curb][0];
      const char* vb = (const char*)&Vlds[curb][0];

      // --- S^T = K Q^T (log2 units, scale pre-folded) ---
      f32x16 sA = {}, sB = {};
#pragma unroll
      for (int kc = 0; kc < 4; ++kc)
        sA = mfma32(*(const ushortx8*)(kb + koff[kc]), qf[kc], sA);
      if (!halfB) {
#pragma unroll
        for (int kc = 0; kc < 4; ++kc)
          sB = mfma32(*(const ushortx8*)(kb + 4096 + koff[kc]), qf[kc], sB);
      }

      // --- causal mask (diag tiles only) ---
      if (diag) {
#pragma unroll
        for (int r = 0; r < 16; ++r) {
          const int krow = (r & 3) + 8 * (r >> 2) + 4 * h;
          if (halfB) { if (krow > l31) sA[r] = -INFINITY; }
          else       { if (krow > l31) sB[r] = -INFINITY; }
        }
      }

      // --- row max (tree) ---
      float mm[16];
#pragma unroll
      for (int r = 0; r < 16; ++r) mm[r] = halfB ? sA[r] : fmaxf(sA[r], sB[r]);
#pragma unroll
      for (int st = 8; st >= 1; st >>= 1)
#pragma unroll
        for (int r = 0; r < st; ++r) mm[r] = fmaxf(mm[r], mm[r + st]);
      const float mx = fmaxf(mm[0], __shfl_xor(mm[0], 32, 64));

      // --- deferred-max rescale (THR=8 in log2 domain) ---
      if (__any(mx > m_r + 8.0f)) {
        const float mn = fmaxf(m_r, mx);
        const float al = exp2f(m_r - mn);
        m_r = mn; l_r *= al;
#pragma unroll
        for (int r = 0; r < 16; ++r) { oA[r] *= al; oB[r] *= al; }
      }

      // --- exp2 + pack bf16 + partial sums ---
      unsigned u[16];
      float ps[8];
#pragma unroll
      for (int jj = 0; jj < 8; ++jj) {
        const float e0 = exp2f(sA[2 * jj] - m_r);
        const float e1 = exp2f(sA[2 * jj + 1] - m_r);
        u[jj] = cvt_pk_bf16(e0, e1);
        ps[jj] = e0 + e1;
      }
      if (!halfB) {
#pragma unroll
        for (int jj = 0; jj < 8; ++jj) {
          const float e0 = exp2f(sB[2 * jj] - m_r);
          const float e1 = exp2f(sB[2 * jj + 1] - m_r);
          u[8 + jj] = cvt_pk_bf16(e0, e1);
          ps[jj] += e0 + e1;
        }
      }
#pragma unroll
      for (int st = 4; st >= 1; st >>= 1)
#pragma unroll
        for (int r = 0; r < st; ++r) ps[r] += ps[r + st];
      l_r += ps[0] + __shfl_xor(ps[0], 32, 64);

      // --- P^T B-frags via permlane32 swaps ---
      plswap(u[0], u[2]);   plswap(u[1], u[3]);
      plswap(u[4], u[6]);   plswap(u[5], u[7]);
      if (!halfB) {
        plswap(u[8], u[10]);  plswap(u[9], u[11]);
        plswap(u[12], u[14]); plswap(u[13], u[15]);
      }

      // --- O^T += V^T P^T ---
#pragma unroll
      for (int kc = 0; kc < 4; ++kc) {
        if (kc < 2 || !halfB) {
          uintx4 pw;
          pw[0] = u[4 * kc + 0]; pw[1] = u[4 * kc + 1];
          pw[2] = u[4 * kc + 2]; pw[3] = u[4 * kc + 3];
          const ushortx8 pav = __builtin_bit_cast(ushortx8, pw);
          oA = mfma32(*(const ushortx8*)(vb + koff[kc]), pav, oA);
          oB = mfma32(*(const ushortx8*)(vb + 4096 + koff[kc]), pav, oB);
        }
      }
    }

    __builtin_amdgcn_s_barrier();   // all reads of buf curb done before overwrite
    asm volatile("" ::: "memory");
    curb ^= 1;
  }

  // ---- epilogue ----
  if (k == 1) {
    const float inv_l = 1.0f / l_r;
    ushort_t* op = O + ((size_t)(b * NT + qg)) * 1024 + head * 64;
#pragma unroll
    for (int db = 0; db < 2; ++db)
#pragma unroll
      for (int g = 0; g < 4; ++g) {
        ushort4 pk;
        pk.x = bf16_rne((db ? oB[4 * g + 0] : oA[4 * g + 0]) * inv_l);
        pk.y = bf16_rne((db ? oB[4 * g + 1] : oA[4 * g + 1]) * inv_l);
        pk.z = bf16_rne((db ? oB[4 * g + 2] : oA[4 * g + 2]) * inv_l);
        pk.w = bf16_rne((db ? oB[4 * g + 3] : oA[4 * g + 3]) * inv_l);
        *(ushort4*)(op + db * 32 + 8 * g + 4 * h) = pk;
      }
  } else {
    const int local = (qb < 8) ? ((qb - 4) * 2 + j)
                    : (qb < 12) ? (8 + (qb - 8) * 3 + j)
                    : (20 + (qb - 12) * 4 + j);
    const int s = bh * 36 + local;
    char* wb = (s < R0_SLOTS ? wsb + (size_t)s * SLOT_BYTES
                             : wsb + PART1_OFF + (size_t)(s - R0_SLOTS) * SLOT_BYTES)
               + w * WAVE_BYTES;
#pragma unroll
    for (int g = 0; g < 4; ++g) {
      ushortx8 pk;
#pragma unroll
      for (int e2 = 0; e2 < 8; ++e2)
        pk[e2] = bf16_rne(g < 2 ? oA[g * 8 + e2] : oB[(g - 2) * 8 + e2]);
      *(ushortx8*)(wb + lane * 64 + g * 16) = pk;
    }
    *(float*)(wb + 4096 + lane * 4) = m_r;
    *(float*)(wb + 4352 + lane * 4) = l_r;
  }
}

// ---------- merge partials for qb >= 4 (max-weighted, R4-proven) ----------
__global__ __launch_bounds__(256)
void attn_merge(const char* __restrict__ wsb, ushort_t* __restrict__ O) {
  const int x = blockIdx.x;   // 384 = 32 bh * 12 qb
  const int bh = x & 31;
  const int qi = x >> 5;      // 0..11 -> qb 4..15
  const int qb = 4 + qi;
  const int k  = qi < 4 ? 2 : (qi < 8 ? 3 : 4);
  const int lb = qi < 4 ? qi * 2 : (qi < 8 ? 8 + (qi - 4) * 3 : 20 + (qi - 8) * 4);
  const int tid = threadIdx.x;
  const int lane = tid & 63;
  const int w = tid >> 6;
  const int l31 = lane & 31;
  const int h = lane >> 5;

  const char* wbs[4];
  float mj[4], lj[4];
  float M = -INFINITY;
#pragma unroll
  for (int jj = 0; jj < 4; ++jj) {
    if (jj < k) {
      const int s = bh * 36 + lb + jj;
      const char* wb = (s < R0_SLOTS ? wsb + (size_t)s * SLOT_BYTES
                                     : wsb + PART1_OFF + (size_t)(s - R0_SLOTS) * SLOT_BYTES)
                       + w * WAVE_BYTES;
      wbs[jj] = wb;
      mj[jj] = *(const float*)(wb + 4096 + lane * 4);
      lj[jj] = *(const float*)(wb + 4352 + lane * 4);
      M = fmaxf(M, mj[jj]);
    }
  }
  float o[32];
#pragma unroll
  for (int r = 0; r < 32; ++r) o[r] = 0.f;
  float lacc = 0.f;
#pragma unroll
  for (int jj = 0; jj < 4; ++jj) {
    if (jj < k) {
      const float a = exp2f(mj[jj] - M);
      lacc += a * lj[jj];
#pragma unroll
      for (int g = 0; g < 4; ++g) {
        const ushortx8 v = *(const ushortx8*)(wbs[jj] + lane * 64 + g * 16);
#pragma unroll
        for (int e = 0; e < 8; ++e) o[g * 8 + e] += a * bf2f(v[e]);
      }
    }
  }
  const float inv_l = 1.0f / lacc;
  const int b = bh >> 4, head = bh & 15;
  const int qg = qb * 128 + w * 32 + l31;
  ushort_t* op = O + ((size_t)(b * NT + qg)) * 1024 + head * 64;
#pragma unroll
  for (int db = 0; db < 2; ++db)
#pragma unroll
    for (int g = 0; g < 4; ++g) {
      ushort4 pk;
      pk.x = bf16_rne(o[db * 16 + 4 * g + 0] * inv_l);
      pk.y = bf16_rne(o[db * 16 + 4 * g + 1] * inv_l);
      pk.z = bf16_rne(o[db * 16 + 4 * g + 2] * inv_l);
      pk.w = bf16_rne(o[db * 16 + 4 * g + 3] * inv_l);
      *(ushort4*)(op + db * 32 + 8 * g + 4 * h) = pk;
    }
}

// ---------- launch ----------

extern "C" void kernel_launch(void* const* d_in, const int* in_sizes, int n_in,
                              void* d_out, int out_size, void* d_ws, size_t ws_size,
                              hipStream_t stream) {
  (void)in_sizes; (void)n_in; (void)out_size; (void)ws_size;
  const float* x  = (const float*)d_in[0];
  const float* Wq = (const float*)d_in[1];
  const float* Wk = (const float*)d_in[2];
  const float* Wv = (const float*)d_in[3];
  const float* Wo = (const float*)d_in[4];

  char* ws = (char*)d_ws;
  ushort_t* Xbf    = (ushort_t*)(ws);                        // 4096x1024 bf16 (8 MB)
  ushort_t* Wqkv_t = (ushort_t*)(ws + 8388608);              // 3072x1024 bf16 (6 MB)
  ushort_t* Wo_bf  = (ushort_t*)(ws + 14680064);             // 1024x1024 bf16 (2 MB)
  ushort_t* QKV    = (ushort_t*)(ws + 16777216);             // 4096x2048 bf16 (16 MB)
  ushort_t* Vt     = (ushort_t*)(ws + 33554432);             // 2048x2048 bf16 (8 MB)
  ushort_t* Obf    = (ushort_t*)(ws + 41943040);             // 4096x1024 bf16 (8 MB)

  pack_cast<<<4096, 256, 0, stream>>>((const float4*)x, Xbf, 1048576);
  pack_cast<<<1024, 256, 0, stream>>>((const float4*)Wo, Wo_bf, 262144);
  pack_wqkv<<<dim3(16, 48), 256, 0, stream>>>(Wq, Wk, Wv, Wqkv_t);

  gemm_bt<1><<<dim3(24, 32), 256, 0, stream>>>(Xbf, Wqkv_t, QKV, Vt, BT, N3, CD);
  attn_fwd7<<<1280, 256, 0, stream>>>(QKV, Vt, Obf, ws);
  attn_merge<<<384, 256, 0, stream>>>(ws, Obf);
  gemm_bt<0><<<dim3(8, 32), 256, 0, stream>>>(Obf, Wo_bf, d_out, nullptr, BT, CD, CD);
}